// Round 1
// baseline (723.842 us; speedup 1.0000x reference)
//
#include <hip/hip_runtime.h>
#include <hip/hip_bf16.h>
#include <stdint.h>

// Problem constants (fixed by the reference)
#define HD      4096            // K (hidden)
#define MROWS   8192            // B*S
#define NQ      4096
#define NKV     1024
#define NTOT    6144            // NQ + 2*NKV
#define RMS_EPS 1e-6f

typedef __attribute__((ext_vector_type(8))) short bf16x8;
typedef __attribute__((ext_vector_type(4))) float f32x4;

static __device__ __forceinline__ unsigned short f2bf(float f) {
  union { float f; unsigned u; } a; a.f = f;
  unsigned r = a.u + 0x7FFFu + ((a.u >> 16) & 1u);   // RNE
  return (unsigned short)(r >> 16);
}

// ---------------- RMSNorm + cast to bf16 ----------------
__global__ __launch_bounds__(256) void rmsnorm_cast_kernel(
    const float* __restrict__ x, const float* __restrict__ gamma,
    unsigned short* __restrict__ xn) {
  const int row = blockIdx.x;                 // 8192 rows
  const float4* xr = (const float4*)(x + (size_t)row * HD);
  const float4* g4 = (const float4*)gamma;
  const int t = threadIdx.x;                  // 256 threads
  float4 v[4];
  float ss = 0.f;
#pragma unroll
  for (int i = 0; i < 4; ++i) {
    v[i] = xr[t + i * 256];
    ss += v[i].x * v[i].x + v[i].y * v[i].y + v[i].z * v[i].z + v[i].w * v[i].w;
  }
#pragma unroll
  for (int o = 32; o > 0; o >>= 1) ss += __shfl_xor(ss, o, 64);
  __shared__ float red[4];
  if ((t & 63) == 0) red[t >> 6] = ss;
  __syncthreads();
  const float tot = red[0] + red[1] + red[2] + red[3];
  const float rstd = rsqrtf(tot * (1.f / HD) + RMS_EPS);
  ushort4* xo = (ushort4*)(xn + (size_t)row * HD);
#pragma unroll
  for (int i = 0; i < 4; ++i) {
    const float4 g = g4[t + i * 256];
    ushort4 o;
    o.x = f2bf(v[i].x * rstd * g.x);
    o.y = f2bf(v[i].y * rstd * g.y);
    o.z = f2bf(v[i].z * rstd * g.z);
    o.w = f2bf(v[i].w * rstd * g.w);
    xo[t + i * 256] = o;
  }
}

// ---------------- Transpose + cast W[K][Nw] f32 -> Wt[Nw][K] bf16 ----------------
__global__ __launch_bounds__(256) void transpose_cast_kernel(
    const float* __restrict__ w, unsigned short* __restrict__ wt, int Nw) {
  __shared__ float tile[32][33];
  const int kt = blockIdx.y;                  // K/32
  const int nb = blockIdx.x;                  // Nw/32
  const int t = threadIdx.x;
  const int r = t >> 3, c4 = t & 7;
  const float4 vin = *(const float4*)&w[(size_t)(kt * 32 + r) * Nw + nb * 32 + c4 * 4];
  tile[r][c4 * 4 + 0] = vin.x;
  tile[r][c4 * 4 + 1] = vin.y;
  tile[r][c4 * 4 + 2] = vin.z;
  tile[r][c4 * 4 + 3] = vin.w;
  __syncthreads();
  ushort4 o;
  o.x = f2bf(tile[c4 * 4 + 0][r]);
  o.y = f2bf(tile[c4 * 4 + 1][r]);
  o.z = f2bf(tile[c4 * 4 + 2][r]);
  o.w = f2bf(tile[c4 * 4 + 3][r]);
  *(ushort4*)&wt[(size_t)(nb * 32 + r) * HD + kt * 32 + c4 * 4] = o;
}

// ---------------- bf16 GEMM: C[M,N] = A[M,K] * Bt[N,K]^T, f32 out to q/k/v ----------------
#define BM 128
#define BN 128
#define BK 32

static __device__ __forceinline__ void gload_lds16(const unsigned short* g,
                                                   unsigned short* l) {
  __builtin_amdgcn_global_load_lds(
      (__attribute__((address_space(1))) void*)g,
      (__attribute__((address_space(3))) void*)l, 16, 0, 0);
}

__global__ __launch_bounds__(256) void gemm_qkv_kernel(
    const unsigned short* __restrict__ A,    // [MROWS][HD] bf16 (xn)
    const unsigned short* __restrict__ Bt,   // [NTOT][HD] bf16 (w^T)
    float* __restrict__ out) {
  __shared__ unsigned short As[BM * BK];     // 8 KB
  __shared__ unsigned short Bs[BN * BK];     // 8 KB

  // bijective XCD swizzle: nwg = 3072 = 8 * 384
  const int bid = blockIdx.x;
  const int swz = (bid & 7) * 384 + (bid >> 3);
  const int mt = swz / 48, nt = swz % 48;    // 64 x 48 tiles
  const int m0 = mt * BM, n0 = nt * BN;

  const int t = threadIdx.x;
  const int w = t >> 6, lane = t & 63;
  const int wr = w >> 1, wc = w & 1;         // 2x2 waves, each 64x64 out
  const int fr = lane & 15, fq = lane >> 4;

  const int srow = lane >> 2;                // staging: row within 16-row group
  const int skoff = (lane & 3) * 8;          // staging: k offset (8 bf16 = 16B)

  f32x4 acc[4][4];
#pragma unroll
  for (int i = 0; i < 4; ++i)
#pragma unroll
    for (int j = 0; j < 4; ++j) acc[i][j] = (f32x4){0.f, 0.f, 0.f, 0.f};

  for (int kk = 0; kk < HD; kk += BK) {
#pragma unroll
    for (int i = 0; i < 2; ++i) {
      const int g = i * 4 + w;               // 16-row group 0..7
      gload_lds16(&A[(size_t)(m0 + g * 16 + srow) * HD + kk + skoff], &As[g * 512]);
      gload_lds16(&Bt[(size_t)(n0 + g * 16 + srow) * HD + kk + skoff], &Bs[g * 512]);
    }
    __syncthreads();                         // drains vmcnt before reads

    bf16x8 a[4], b[4];
#pragma unroll
    for (int i = 0; i < 4; ++i)
      a[i] = *(const bf16x8*)&As[(wr * 64 + i * 16 + fr) * BK + fq * 8];
#pragma unroll
    for (int j = 0; j < 4; ++j)
      b[j] = *(const bf16x8*)&Bs[(wc * 64 + j * 16 + fr) * BK + fq * 8];
#pragma unroll
    for (int i = 0; i < 4; ++i)
#pragma unroll
      for (int j = 0; j < 4; ++j)
        acc[i][j] = __builtin_amdgcn_mfma_f32_16x16x32_bf16(a[i], b[j], acc[i][j], 0, 0, 0);

    __syncthreads();                         // before next-stage overwrite
  }

  // epilogue: route this block's 128 columns to q / k / v region
  size_t base; int ldc, nc;
  if (n0 < NQ)              { base = 0;                                        ldc = NQ;  nc = n0; }
  else if (n0 < NQ + NKV)   { base = (size_t)MROWS * NQ;                       ldc = NKV; nc = n0 - NQ; }
  else                      { base = (size_t)MROWS * NQ + (size_t)MROWS * NKV; ldc = NKV; nc = n0 - NQ - NKV; }

#pragma unroll
  for (int i = 0; i < 4; ++i) {
#pragma unroll
    for (int j = 0; j < 4; ++j) {
      const int r0 = m0 + wr * 64 + i * 16 + fq * 4;
      const int c  = nc + wc * 64 + j * 16 + fr;
#pragma unroll
      for (int jj = 0; jj < 4; ++jj)
        out[base + (size_t)(r0 + jj) * ldc + c] = acc[i][j][jj];
    }
  }
}

extern "C" void kernel_launch(void* const* d_in, const int* in_sizes, int n_in,
                              void* d_out, int out_size, void* d_ws, size_t ws_size,
                              hipStream_t stream) {
  const float* x     = (const float*)d_in[0];
  const float* gamma = (const float*)d_in[1];
  const float* wq    = (const float*)d_in[2];
  const float* wk    = (const float*)d_in[3];
  const float* wv    = (const float*)d_in[4];
  float* out = (float*)d_out;

  // workspace layout: xn bf16 [8192][4096] then wt bf16 [6144][4096]
  unsigned short* xn = (unsigned short*)d_ws;
  unsigned short* wt = xn + (size_t)MROWS * HD;

  rmsnorm_cast_kernel<<<MROWS, 256, 0, stream>>>(x, gamma, xn);
  transpose_cast_kernel<<<dim3(NQ / 32, HD / 32), 256, 0, stream>>>(wq, wt, NQ);
  transpose_cast_kernel<<<dim3(NKV / 32, HD / 32), 256, 0, stream>>>(
      wk, wt + (size_t)NQ * HD, NKV);
  transpose_cast_kernel<<<dim3(NKV / 32, HD / 32), 256, 0, stream>>>(
      wv, wt + (size_t)(NQ + NKV) * HD, NKV);
  gemm_qkv_kernel<<<(MROWS / BM) * (NTOT / BN), 256, 0, stream>>>(xn, wt, out);
}

// Round 2
// 453.163 us; speedup vs baseline: 1.5973x; 1.5973x over previous
//
#include <hip/hip_runtime.h>
#include <hip/hip_bf16.h>
#include <stdint.h>

// Problem constants (fixed by the reference)
#define HD      4096            // K (hidden)
#define MROWS   8192            // B*S
#define NQ      4096
#define NKV     1024
#define NTOT    6144            // NQ + 2*NKV
#define RMS_EPS 1e-6f

typedef __attribute__((ext_vector_type(8))) short bf16x8;
typedef __attribute__((ext_vector_type(4))) float f32x4;

static __device__ __forceinline__ unsigned short f2bf(float f) {
  union { float f; unsigned u; } a; a.f = f;
  unsigned r = a.u + 0x7FFFu + ((a.u >> 16) & 1u);   // RNE
  return (unsigned short)(r >> 16);
}

// ---------------- RMSNorm + cast to bf16 ----------------
__global__ __launch_bounds__(256) void rmsnorm_cast_kernel(
    const float* __restrict__ x, const float* __restrict__ gamma,
    unsigned short* __restrict__ xn) {
  const int row = blockIdx.x;                 // 8192 rows
  const float4* xr = (const float4*)(x + (size_t)row * HD);
  const float4* g4 = (const float4*)gamma;
  const int t = threadIdx.x;                  // 256 threads
  float4 v[4];
  float ss = 0.f;
#pragma unroll
  for (int i = 0; i < 4; ++i) {
    v[i] = xr[t + i * 256];
    ss += v[i].x * v[i].x + v[i].y * v[i].y + v[i].z * v[i].z + v[i].w * v[i].w;
  }
#pragma unroll
  for (int o = 32; o > 0; o >>= 1) ss += __shfl_xor(ss, o, 64);
  __shared__ float red[4];
  if ((t & 63) == 0) red[t >> 6] = ss;
  __syncthreads();
  const float tot = red[0] + red[1] + red[2] + red[3];
  const float rstd = rsqrtf(tot * (1.f / HD) + RMS_EPS);
  ushort4* xo = (ushort4*)(xn + (size_t)row * HD);
#pragma unroll
  for (int i = 0; i < 4; ++i) {
    const float4 g = g4[t + i * 256];
    ushort4 o;
    o.x = f2bf(v[i].x * rstd * g.x);
    o.y = f2bf(v[i].y * rstd * g.y);
    o.z = f2bf(v[i].z * rstd * g.z);
    o.w = f2bf(v[i].w * rstd * g.w);
    xo[t + i * 256] = o;
  }
}

// ---------------- Transpose + cast W[K][Nw] f32 -> Wt[Nw][K] bf16 ----------------
__global__ __launch_bounds__(256) void transpose_cast_kernel(
    const float* __restrict__ w, unsigned short* __restrict__ wt, int Nw) {
  __shared__ float tile[32][33];
  const int kt = blockIdx.y;                  // K/32
  const int nb = blockIdx.x;                  // Nw/32
  const int t = threadIdx.x;
  const int r = t >> 3, c4 = t & 7;
  const float4 vin = *(const float4*)&w[(size_t)(kt * 32 + r) * Nw + nb * 32 + c4 * 4];
  tile[r][c4 * 4 + 0] = vin.x;
  tile[r][c4 * 4 + 1] = vin.y;
  tile[r][c4 * 4 + 2] = vin.z;
  tile[r][c4 * 4 + 3] = vin.w;
  __syncthreads();
  ushort4 o;
  o.x = f2bf(tile[c4 * 4 + 0][r]);
  o.y = f2bf(tile[c4 * 4 + 1][r]);
  o.z = f2bf(tile[c4 * 4 + 2][r]);
  o.w = f2bf(tile[c4 * 4 + 3][r]);
  *(ushort4*)&wt[(size_t)(nb * 32 + r) * HD + kt * 32 + c4 * 4] = o;
}

// ---------------- 256x256 8-phase bf16 GEMM (T2+T3+T4+T5) ----------------
// C[M,N] = A[M,K] * Bt[N,K]^T ; M=8192, N=6144, K=4096. BK=64, 512 thr.

static __device__ __forceinline__ void gload_lds16(const unsigned short* g,
                                                   unsigned short* l) {
  __builtin_amdgcn_global_load_lds(
      (const __attribute__((address_space(1))) void*)g,
      (__attribute__((address_space(3))) void*)l, 16, 0, 0);
}

#define VM4 asm volatile("s_waitcnt vmcnt(4)" ::: "memory")
#define VM0 asm volatile("s_waitcnt vmcnt(0)" ::: "memory")
#define VMNONE ((void)0)

// Phase: read 12 b128 fragments from lds[.][BUF][HA/HB], issue stage (VA_ARGS),
// barrier, 16 MFMA under setprio, optional counted vmcnt, barrier.
#define PHASE(BUF, HA, HB, VM, ...)                                            \
  do {                                                                         \
    const unsigned short* Ah = &lds[0][BUF][HA][0];                            \
    const unsigned short* Bh = &lds[1][BUF][HB][0];                            \
    bf16x8 af[4][2];                                                           \
    bf16x8 bfr[2][2];                                                          \
    _Pragma("unroll") for (int im = 0; im < 4; ++im) {                         \
      const int r = wr * 64 + im * 16 + fr;                                    \
      af[im][0] = *(const bf16x8*)((const char*)Ah + r * 128 + kb0);           \
      af[im][1] = *(const bf16x8*)((const char*)Ah + r * 128 + (kb0 ^ 64));    \
    }                                                                          \
    _Pragma("unroll") for (int jn = 0; jn < 2; ++jn) {                         \
      const int rb = wc * 32 + jn * 16 + fr;                                   \
      bfr[jn][0] = *(const bf16x8*)((const char*)Bh + rb * 128 + kb0);         \
      bfr[jn][1] = *(const bf16x8*)((const char*)Bh + rb * 128 + (kb0 ^ 64));  \
    }                                                                          \
    __VA_ARGS__;                                                               \
    __builtin_amdgcn_s_barrier();                                              \
    __builtin_amdgcn_s_setprio(1);                                             \
    _Pragma("unroll") for (int ks = 0; ks < 2; ++ks)                           \
      _Pragma("unroll") for (int im = 0; im < 4; ++im)                         \
        _Pragma("unroll") for (int jn = 0; jn < 2; ++jn)                       \
          acc[(HA) * 4 + im][(HB) * 2 + jn] =                                  \
              __builtin_amdgcn_mfma_f32_16x16x32_bf16(                         \
                  af[im][ks], bfr[jn][ks], acc[(HA) * 4 + im][(HB) * 2 + jn],  \
                  0, 0, 0);                                                    \
    __builtin_amdgcn_s_setprio(0);                                             \
    VM;                                                                        \
    __builtin_amdgcn_s_barrier();                                              \
  } while (0)

__global__ __launch_bounds__(512, 2) void gemm_qkv_kernel(
    const unsigned short* __restrict__ A,    // [MROWS][HD] bf16 (xn)
    const unsigned short* __restrict__ Bt,   // [NTOT][HD] bf16 (w^T)
    float* __restrict__ out) {
  // [mat A/B][buf][half][128 rows x 64 k] bf16 = 128 KiB total
  __shared__ unsigned short lds[2][2][2][8192] __attribute__((aligned(16)));

  // bijective XCD swizzle: nwg = 768 = 8 * 96
  const int bid = blockIdx.x;
  const int swz = (bid & 7) * 96 + (bid >> 3);
  const int mt = swz / 24, nt = swz % 24;
  const int m0 = mt * 256, n0 = nt * 256;

  const int tid = threadIdx.x;
  const int w = tid >> 6, lane = tid & 63;
  const int wr = w >> 2, wc = w & 3;         // 2 x 4 waves, each 128x64 out
  const int fr = lane & 15, fq = lane >> 4;
  // swizzled k-byte offset for ds_read (involution with stage-side swizzle)
  const int kb0 = ((lane >> 4) << 4) ^ ((fr & 7) << 4);

  // staging: linear LDS dest, inverse-swizzled global source (rule #21)
  const int wslot = w * 512;                 // wave-uniform LDS element base
  const int r3 = tid >> 3;                   // row 0..63 within pass
  const int scolb = ((tid & 7) << 4) ^ ((r3 & 7) << 4);
  const size_t so0 = (size_t)r3 * HD + (scolb >> 1);
  const size_t so1 = so0 + (size_t)64 * HD;

  const unsigned short* const Ab0 = A + (size_t)m0 * HD;
  const unsigned short* const Ab1 = Ab0 + (size_t)128 * HD;
  const unsigned short* const Bb0 = Bt + (size_t)n0 * HD;
  const unsigned short* const Bb1 = Bb0 + (size_t)128 * HD;

  auto STG = [&](const unsigned short* g, unsigned short* l) {
    gload_lds16(g + so0, l + wslot);
    gload_lds16(g + so1, l + 4096 + wslot);
  };

  f32x4 acc[8][4];
#pragma unroll
  for (int i = 0; i < 8; ++i)
#pragma unroll
    for (int j = 0; j < 4; ++j) acc[i][j] = (f32x4){0.f, 0.f, 0.f, 0.f};

  // prologue: tile0 -> buf0 (all 4 halves), tile1 A0/B0 -> buf1
  STG(Ab0, &lds[0][0][0][0]);
  STG(Bb0, &lds[1][0][0][0]);
  STG(Ab1, &lds[0][0][1][0]);
  STG(Bb1, &lds[1][0][1][0]);
  STG(Ab0 + 64, &lds[0][1][0][0]);
  STG(Bb0 + 64, &lds[1][1][0][0]);
  VM4;                                       // first 8 loads (tile0) landed
  __builtin_amdgcn_s_barrier();

  // 64 K-tiles, 2 per iteration; last iteration peeled (no forward stage)
  for (int t = 0; t < 31; ++t) {
    const size_t k1 = (size_t)(2 * t + 1) * 64;
    const size_t o2 = (size_t)(2 * t + 2) * 64;
    const size_t o3 = (size_t)(2 * t + 3) * 64;
    PHASE(0, 0, 0, VMNONE, STG(Ab1 + k1, &lds[0][1][1][0]));  // p0
    PHASE(0, 0, 1, VMNONE, STG(Bb1 + k1, &lds[1][1][1][0]));  // p1
    PHASE(0, 1, 0, VMNONE, STG(Ab0 + o2, &lds[0][0][0][0]));  // p2
    PHASE(0, 1, 1, VM4,    STG(Bb0 + o2, &lds[1][0][0][0]));  // p3
    PHASE(1, 0, 0, VMNONE, STG(Ab1 + o2, &lds[0][0][1][0]));  // p4
    PHASE(1, 0, 1, VMNONE, STG(Bb1 + o2, &lds[1][0][1][0]));  // p5
    PHASE(1, 1, 0, VMNONE, STG(Ab0 + o3, &lds[0][1][0][0]));  // p6
    PHASE(1, 1, 1, VM4,    STG(Bb0 + o3, &lds[1][1][0][0]));  // p7
  }
  {                                          // t = 31: tiles 62 (buf0), 63 (buf1)
    const size_t k1 = (size_t)63 * 64;
    PHASE(0, 0, 0, VMNONE, STG(Ab1 + k1, &lds[0][1][1][0]));
    PHASE(0, 0, 1, VMNONE, STG(Bb1 + k1, &lds[1][1][1][0]));
    PHASE(0, 1, 0, VMNONE, VMNONE);
    PHASE(0, 1, 1, VM0,    VMNONE);          // buf1 fully landed
    PHASE(1, 0, 0, VMNONE, VMNONE);
    PHASE(1, 0, 1, VMNONE, VMNONE);
    PHASE(1, 1, 0, VMNONE, VMNONE);
    PHASE(1, 1, 1, VMNONE, VMNONE);
  }

  // epilogue: route this block's 256 columns to q / k / v region
  size_t obase; int ldc, nc;
  if (n0 < NQ)            { obase = 0;                                        ldc = NQ;  nc = n0; }
  else if (n0 < NQ + NKV) { obase = (size_t)MROWS * NQ;                       ldc = NKV; nc = n0 - NQ; }
  else                    { obase = (size_t)MROWS * NQ + (size_t)MROWS * NKV; ldc = NKV; nc = n0 - NQ - NKV; }

#pragma unroll
  for (int I = 0; I < 8; ++I) {
    const int rown = m0 + (I >> 2) * 128 + wr * 64 + (I & 3) * 16 + fq * 4;
#pragma unroll
    for (int J = 0; J < 4; ++J) {
      const int col = nc + (J >> 1) * 128 + wc * 32 + (J & 1) * 16 + fr;
#pragma unroll
      for (int jj = 0; jj < 4; ++jj)
        out[obase + (size_t)(rown + jj) * ldc + col] = acc[I][J][jj];
    }
  }
}

extern "C" void kernel_launch(void* const* d_in, const int* in_sizes, int n_in,
                              void* d_out, int out_size, void* d_ws, size_t ws_size,
                              hipStream_t stream) {
  const float* x     = (const float*)d_in[0];
  const float* gamma = (const float*)d_in[1];
  const float* wq    = (const float*)d_in[2];
  const float* wk    = (const float*)d_in[3];
  const float* wv    = (const float*)d_in[4];
  float* out = (float*)d_out;

  // workspace layout: xn bf16 [8192][4096] then wt bf16 [6144][4096]
  unsigned short* xn = (unsigned short*)d_ws;
  unsigned short* wt = xn + (size_t)MROWS * HD;

  rmsnorm_cast_kernel<<<MROWS, 256, 0, stream>>>(x, gamma, xn);
  transpose_cast_kernel<<<dim3(NQ / 32, HD / 32), 256, 0, stream>>>(wq, wt, NQ);
  transpose_cast_kernel<<<dim3(NKV / 32, HD / 32), 256, 0, stream>>>(
      wk, wt + (size_t)NQ * HD, NKV);
  transpose_cast_kernel<<<dim3(NKV / 32, HD / 32), 256, 0, stream>>>(
      wv, wt + (size_t)(NQ + NKV) * HD, NKV);
  gemm_qkv_kernel<<<(MROWS / 256) * (NTOT / 256), 512, 0, stream>>>(xn, wt, out);
}

// Round 3
// 409.867 us; speedup vs baseline: 1.7660x; 1.1056x over previous
//
#include <hip/hip_runtime.h>
#include <hip/hip_bf16.h>
#include <stdint.h>

// Problem constants (fixed by the reference)
#define HD      4096            // K (hidden)
#define MROWS   8192            // B*S
#define NQ      4096
#define NKV     1024
#define NTOT    6144            // NQ + 2*NKV
#define RMS_EPS 1e-6f

typedef __attribute__((ext_vector_type(8))) short bf16x8;
typedef __attribute__((ext_vector_type(4))) float f32x4;

static __device__ __forceinline__ unsigned short f2bf(float f) {
  union { float f; unsigned u; } a; a.f = f;
  unsigned r = a.u + 0x7FFFu + ((a.u >> 16) & 1u);   // RNE
  return (unsigned short)(r >> 16);
}

// ---------------- RMSNorm + cast to bf16 ----------------
__global__ __launch_bounds__(256) void rmsnorm_cast_kernel(
    const float* __restrict__ x, const float* __restrict__ gamma,
    unsigned short* __restrict__ xn) {
  const int row = blockIdx.x;                 // 8192 rows
  const float4* xr = (const float4*)(x + (size_t)row * HD);
  const float4* g4 = (const float4*)gamma;
  const int t = threadIdx.x;                  // 256 threads
  float4 v[4];
  float ss = 0.f;
#pragma unroll
  for (int i = 0; i < 4; ++i) {
    v[i] = xr[t + i * 256];
    ss += v[i].x * v[i].x + v[i].y * v[i].y + v[i].z * v[i].z + v[i].w * v[i].w;
  }
#pragma unroll
  for (int o = 32; o > 0; o >>= 1) ss += __shfl_xor(ss, o, 64);
  __shared__ float red[4];
  if ((t & 63) == 0) red[t >> 6] = ss;
  __syncthreads();
  const float tot = red[0] + red[1] + red[2] + red[3];
  const float rstd = rsqrtf(tot * (1.f / HD) + RMS_EPS);
  ushort4* xo = (ushort4*)(xn + (size_t)row * HD);
#pragma unroll
  for (int i = 0; i < 4; ++i) {
    const float4 g = g4[t + i * 256];
    ushort4 o;
    o.x = f2bf(v[i].x * rstd * g.x);
    o.y = f2bf(v[i].y * rstd * g.y);
    o.z = f2bf(v[i].z * rstd * g.z);
    o.w = f2bf(v[i].w * rstd * g.w);
    xo[t + i * 256] = o;
  }
}

// ---------------- Transpose + cast W[K][Nw] f32 -> Wt[Nw][K] bf16 ----------------
__global__ __launch_bounds__(256) void transpose_cast_kernel(
    const float* __restrict__ w, unsigned short* __restrict__ wt, int Nw) {
  __shared__ float tile[32][33];
  const int kt = blockIdx.y;                  // K/32
  const int nb = blockIdx.x;                  // Nw/32
  const int t = threadIdx.x;
  const int r = t >> 3, c4 = t & 7;
  const float4 vin = *(const float4*)&w[(size_t)(kt * 32 + r) * Nw + nb * 32 + c4 * 4];
  tile[r][c4 * 4 + 0] = vin.x;
  tile[r][c4 * 4 + 1] = vin.y;
  tile[r][c4 * 4 + 2] = vin.z;
  tile[r][c4 * 4 + 3] = vin.w;
  __syncthreads();
  ushort4 o;
  o.x = f2bf(tile[c4 * 4 + 0][r]);
  o.y = f2bf(tile[c4 * 4 + 1][r]);
  o.z = f2bf(tile[c4 * 4 + 2][r]);
  o.w = f2bf(tile[c4 * 4 + 3][r]);
  *(ushort4*)&wt[(size_t)(nb * 32 + r) * HD + kt * 32 + c4 * 4] = o;
}

// ---------------- 256x256 8-phase bf16 GEMM (T2+T3+T4+T5) ----------------
// C[M,N] = A[M,K] * Bt[N,K]^T ; M=8192, N=6144, K=4096. BK=64, 512 thr.

static __device__ __forceinline__ void gload_lds16(const unsigned short* g,
                                                   unsigned short* l) {
  __builtin_amdgcn_global_load_lds(
      (const __attribute__((address_space(1))) void*)g,
      (__attribute__((address_space(3))) void*)l, 16, 0, 0);
}

#define VM4 asm volatile("s_waitcnt vmcnt(4)" ::: "memory")
#define VM0 asm volatile("s_waitcnt vmcnt(0)" ::: "memory")
#define VMNONE ((void)0)

// ds-read the 8 A fragments of half HA (held across a phase pair)
#define READS_A(BUF, HA)                                                       \
  do {                                                                         \
    const unsigned short* Ah = &lds[0][BUF][HA][0];                            \
    _Pragma("unroll") for (int im = 0; im < 4; ++im) {                         \
      const int r = wr * 64 + im * 16 + fr;                                    \
      af[im][0] = *(const bf16x8*)((const char*)Ah + r * 128 + kb0);           \
      af[im][1] = *(const bf16x8*)((const char*)Ah + r * 128 + (kb0 ^ 64));    \
    }                                                                          \
  } while (0)

// ds-read the 4 B fragments of half HB
#define READS_B(BUF, HB)                                                       \
  do {                                                                         \
    const unsigned short* Bh = &lds[1][BUF][HB][0];                            \
    _Pragma("unroll") for (int jn = 0; jn < 2; ++jn) {                         \
      const int rb = wc * 32 + jn * 16 + fr;                                   \
      bfr[jn][0] = *(const bf16x8*)((const char*)Bh + rb * 128 + kb0);         \
      bfr[jn][1] = *(const bf16x8*)((const char*)Bh + rb * 128 + (kb0 ^ 64));  \
    }                                                                          \
  } while (0)

// barrier -> 16 MFMA (C quadrant HA x HB over K=64) under setprio -> VM -> barrier
#define MMA(HA, HB, VM)                                                        \
  do {                                                                         \
    __builtin_amdgcn_s_barrier();                                              \
    __builtin_amdgcn_s_setprio(1);                                             \
    _Pragma("unroll") for (int ks = 0; ks < 2; ++ks)                           \
      _Pragma("unroll") for (int im = 0; im < 4; ++im)                         \
        _Pragma("unroll") for (int jn = 0; jn < 2; ++jn)                       \
          acc[(HA) * 4 + im][(HB) * 2 + jn] =                                  \
              __builtin_amdgcn_mfma_f32_16x16x32_bf16(                         \
                  af[im][ks], bfr[jn][ks], acc[(HA) * 4 + im][(HB) * 2 + jn],  \
                  0, 0, 0);                                                    \
    __builtin_amdgcn_s_setprio(0);                                             \
    VM;                                                                        \
    __builtin_amdgcn_s_barrier();                                              \
  } while (0)

// Phase pair: A-frags hoisted (read once), B-frags per phase.
#define PAIR(BUF, HA, STG1, VM1, STG2, VM2)                                    \
  do {                                                                         \
    READS_A(BUF, HA);                                                          \
    READS_B(BUF, 0);                                                           \
    STG1;                                                                      \
    MMA(HA, 0, VM1);                                                           \
    READS_B(BUF, 1);                                                           \
    STG2;                                                                      \
    MMA(HA, 1, VM2);                                                           \
  } while (0)

__global__ __launch_bounds__(512, 2) void gemm_qkv_kernel(
    const unsigned short* __restrict__ A,    // [MROWS][HD] bf16 (xn)
    const unsigned short* __restrict__ Bt,   // [NTOT][HD] bf16 (w^T)
    float* __restrict__ out) {
  // [mat A/B][buf][half][128 rows x 64 k] bf16 = 128 KiB total
  __shared__ unsigned short lds[2][2][2][8192] __attribute__((aligned(16)));

  // XCD-rectangular swizzle: grid 32mt x 24nt = 768 blocks, XCD = bid&7.
  // Each XCD owns an 8mt x 12nt chunk (4x2 chunk grid); within a chunk,
  // dispatch order fills 8mt x 4nt rectangles (32 blocks = 1 CU round) so the
  // concurrently-resident set shares A-panels x4 and B-panels x8 in its L2.
  const int bid = blockIdx.x;
  const int xcd = bid & 7;
  const int idx = bid >> 3;                  // 0..95
  const int sr  = idx >> 5;                  // sub-round 0..2
  const int i32 = idx & 31;
  const int mt  = (xcd >> 1) * 8 + (i32 >> 2);
  const int nt  = (xcd & 1) * 12 + sr * 4 + (i32 & 3);
  const int m0 = mt * 256, n0 = nt * 256;

  const int tid = threadIdx.x;
  const int w = tid >> 6, lane = tid & 63;
  const int wr = w >> 2, wc = w & 3;         // 2 x 4 waves, each 128x64 out
  const int fr = lane & 15, fq = lane >> 4;
  // swizzled k-byte offset for ds_read (involution with stage-side swizzle)
  const int kb0 = ((lane >> 4) << 4) ^ ((fr & 7) << 4);

  // staging: linear LDS dest, inverse-swizzled global source (rule #21)
  const int wslot = w * 512;                 // wave-uniform LDS element base
  const int r3 = tid >> 3;                   // row 0..63 within pass
  const int scolb = ((tid & 7) << 4) ^ ((r3 & 7) << 4);
  const size_t so0 = (size_t)r3 * HD + (scolb >> 1);
  const size_t so1 = so0 + (size_t)64 * HD;

  const unsigned short* const Ab0 = A + (size_t)m0 * HD;
  const unsigned short* const Ab1 = Ab0 + (size_t)128 * HD;
  const unsigned short* const Bb0 = Bt + (size_t)n0 * HD;
  const unsigned short* const Bb1 = Bb0 + (size_t)128 * HD;

  auto STG = [&](const unsigned short* g, unsigned short* l) {
    gload_lds16(g + so0, l + wslot);
    gload_lds16(g + so1, l + 4096 + wslot);
  };

  f32x4 acc[8][4];
#pragma unroll
  for (int i = 0; i < 8; ++i)
#pragma unroll
    for (int j = 0; j < 4; ++j) acc[i][j] = (f32x4){0.f, 0.f, 0.f, 0.f};

  bf16x8 af[4][2];
  bf16x8 bfr[2][2];

  // prologue: tile0 -> buf0 (all 4 halves), tile1 A0/B0 -> buf1
  STG(Ab0, &lds[0][0][0][0]);
  STG(Bb0, &lds[1][0][0][0]);
  STG(Ab1, &lds[0][0][1][0]);
  STG(Bb1, &lds[1][0][1][0]);
  STG(Ab0 + 64, &lds[0][1][0][0]);
  STG(Bb0 + 64, &lds[1][1][0][0]);
  VM4;                                       // first 8 loads (tile0) landed
  __builtin_amdgcn_s_barrier();

  // 64 K-tiles, 2 per iteration; last iteration peeled (no forward stage)
  for (int t = 0; t < 31; ++t) {
    const size_t k1 = (size_t)(2 * t + 1) * 64;
    const size_t o2 = (size_t)(2 * t + 2) * 64;
    const size_t o3 = (size_t)(2 * t + 3) * 64;
    PAIR(0, 0, STG(Ab1 + k1, &lds[0][1][1][0]), VMNONE,
               STG(Bb1 + k1, &lds[1][1][1][0]), VMNONE);
    PAIR(0, 1, STG(Ab0 + o2, &lds[0][0][0][0]), VMNONE,
               STG(Bb0 + o2, &lds[1][0][0][0]), VM4);
    PAIR(1, 0, STG(Ab1 + o2, &lds[0][0][1][0]), VMNONE,
               STG(Bb1 + o2, &lds[1][0][1][0]), VMNONE);
    PAIR(1, 1, STG(Ab0 + o3, &lds[0][1][0][0]), VMNONE,
               STG(Bb0 + o3, &lds[1][1][0][0]), VM4);
  }
  {                                          // t = 31: tiles 62 (buf0), 63 (buf1)
    const size_t k1 = (size_t)63 * 64;
    PAIR(0, 0, STG(Ab1 + k1, &lds[0][1][1][0]), VMNONE,
               STG(Bb1 + k1, &lds[1][1][1][0]), VMNONE);
    PAIR(0, 1, VMNONE, VMNONE, VMNONE, VM0); // buf1 fully landed
    PAIR(1, 0, VMNONE, VMNONE, VMNONE, VMNONE);
    PAIR(1, 1, VMNONE, VMNONE, VMNONE, VMNONE);
  }

  // epilogue: route this block's 256 columns to q / k / v region
  size_t obase; int ldc, nc;
  if (n0 < NQ)            { obase = 0;                                        ldc = NQ;  nc = n0; }
  else if (n0 < NQ + NKV) { obase = (size_t)MROWS * NQ;                       ldc = NKV; nc = n0 - NQ; }
  else                    { obase = (size_t)MROWS * NQ + (size_t)MROWS * NKV; ldc = NKV; nc = n0 - NQ - NKV; }

#pragma unroll
  for (int I = 0; I < 8; ++I) {
    const int rown = m0 + (I >> 2) * 128 + wr * 64 + (I & 3) * 16 + fq * 4;
#pragma unroll
    for (int J = 0; J < 4; ++J) {
      const int col = nc + (J >> 1) * 128 + wc * 32 + (J & 1) * 16 + fr;
#pragma unroll
      for (int jj = 0; jj < 4; ++jj)
        out[obase + (size_t)(rown + jj) * ldc + col] = acc[I][J][jj];
    }
  }
}

extern "C" void kernel_launch(void* const* d_in, const int* in_sizes, int n_in,
                              void* d_out, int out_size, void* d_ws, size_t ws_size,
                              hipStream_t stream) {
  const float* x     = (const float*)d_in[0];
  const float* gamma = (const float*)d_in[1];
  const float* wq    = (const float*)d_in[2];
  const float* wk    = (const float*)d_in[3];
  const float* wv    = (const float*)d_in[4];
  float* out = (float*)d_out;

  // workspace layout: xn bf16 [8192][4096] then wt bf16 [6144][4096]
  unsigned short* xn = (unsigned short*)d_ws;
  unsigned short* wt = xn + (size_t)MROWS * HD;

  rmsnorm_cast_kernel<<<MROWS, 256, 0, stream>>>(x, gamma, xn);
  transpose_cast_kernel<<<dim3(NQ / 32, HD / 32), 256, 0, stream>>>(wq, wt, NQ);
  transpose_cast_kernel<<<dim3(NKV / 32, HD / 32), 256, 0, stream>>>(
      wk, wt + (size_t)NQ * HD, NKV);
  transpose_cast_kernel<<<dim3(NKV / 32, HD / 32), 256, 0, stream>>>(
      wv, wt + (size_t)(NQ + NKV) * HD, NKV);
  gemm_qkv_kernel<<<(MROWS / 256) * (NTOT / 256), 512, 0, stream>>>(xn, wt, out);
}